// Round 1
// baseline (424.567 us; speedup 1.0000x reference)
//
#include <hip/hip_runtime.h>
#include <stdint.h>

typedef unsigned long long u64;
typedef unsigned int u32;
typedef unsigned short u16;

struct InPtrs { const float* p[37]; };

// workspace layout (bytes)
#define OFF_WS1    0         // float[144]   stem signed weights
#define OFF_THR1   1024      // double[16]   stem thresholds
#define OFF_WAM    1536      // u32[32]      1x1 branch masks
#define OFF_WBP    2048      // u64[32*3]    3x3 branch masks (4 taps per u64)
#define OFF_WCP    4096      // u64[32*8]    5x5 branch masks (stride 8, 7 used)
#define OFF_THRA   6144      // float[32]
#define OFF_THRB   6400      // float[32]
#define OFF_THRC   6656      // float[32]
#define OFF_THRF1  8192      // float[1024]
#define OFF_WF2P   12288     // u64[160]
#define OFF_A2     13568     // float[10]
#define OFF_C2     13632     // float[10]
#define OFF_WF1P   16384     // u64[1024*74]
#define OFF_H1     655360    // u16[B*196]
#define OFF_H2     2621440   // u64[B*74]
#define OFF_HB2    5242880   // u64[B*16]

// ---------------------------------------------------------------- W0: small packs
__global__ __launch_bounds__(256) void kprep(InPtrs P, char* __restrict__ ws) {
  const float* w1 = P.p[1]; const float* b1 = P.p[2];
  const float* g1 = P.p[3]; const float* bt1 = P.p[4]; const float* m1 = P.p[5]; const float* v1 = P.p[6];
  const float* wa = P.p[7]; const float* ba = P.p[8];
  const float* ag = P.p[9]; const float* abt = P.p[10]; const float* am = P.p[11]; const float* av = P.p[12];
  const float* wb = P.p[13]; const float* bb = P.p[14];
  const float* bg = P.p[15]; const float* bbt = P.p[16]; const float* bm = P.p[17]; const float* bv = P.p[18];
  const float* wc = P.p[19]; const float* bc = P.p[20];
  const float* cg = P.p[21]; const float* cbt = P.p[22]; const float* cm = P.p[23]; const float* cv = P.p[24];
  const float* bf1 = P.p[26];
  const float* f1g = P.p[27]; const float* f1bt = P.p[28]; const float* f1m = P.p[29]; const float* f1v = P.p[30];
  const float* wf2 = P.p[31]; const float* bf2 = P.p[32];
  const float* f2g = P.p[33]; const float* f2bt = P.p[34]; const float* f2m = P.p[35]; const float* f2v = P.p[36];

  float* ws1  = (float*)(ws + OFF_WS1);
  double* thr1 = (double*)(ws + OFF_THR1);
  u32* wam = (u32*)(ws + OFF_WAM);
  u64* wbp = (u64*)(ws + OFF_WBP);
  u64* wcp = (u64*)(ws + OFF_WCP);
  float* thra = (float*)(ws + OFF_THRA);
  float* thrb = (float*)(ws + OFF_THRB);
  float* thrc = (float*)(ws + OFF_THRC);
  float* thrf1 = (float*)(ws + OFF_THRF1);
  u64* wf2p = (u64*)(ws + OFF_WF2P);
  float* a2 = (float*)(ws + OFF_A2);
  float* c2 = (float*)(ws + OFF_C2);

  int t = threadIdx.x;
  for (int i = t; i < 144; i += 256) ws1[i] = (w1[i] >= 0.f) ? 1.f : -1.f;
  if (t < 16) {
    double inv = (double)g1[t] / sqrt((double)v1[t] + 1e-5);
    thr1[t] = (double)m1[t] - (double)bt1[t] / inv - (double)b1[t];
  }
  if (t < 32) {
    u32 m = 0;
    for (int c = 0; c < 16; c++) if (wa[t*16+c] >= 0.f) m |= 1u << c;
    wam[t] = m;
    u64 qb[3] = {0,0,0};
    for (int tt = 0; tt < 9; tt++)
      for (int c = 0; c < 16; c++)
        if (wb[t*144 + c*9 + tt] >= 0.f) qb[tt>>2] |= 1ull << ((tt&3)*16 + c);
    wbp[t*3+0]=qb[0]; wbp[t*3+1]=qb[1]; wbp[t*3+2]=qb[2];
    u64 qc[7] = {0,0,0,0,0,0,0};
    for (int tt = 0; tt < 25; tt++)
      for (int c = 0; c < 16; c++)
        if (wc[t*400 + c*25 + tt] >= 0.f) qc[tt>>2] |= 1ull << ((tt&3)*16 + c);
    for (int k = 0; k < 7; k++) wcp[t*8+k] = qc[k];
    wcp[t*8+7] = 0;
    double ia = (double)ag[t] / sqrt((double)av[t] + 1e-5);
    thra[t] = (float)((double)am[t] - (double)abt[t]/ia - (double)ba[t]);
    double ib = (double)bg[t] / sqrt((double)bv[t] + 1e-5);
    thrb[t] = (float)((double)bm[t] - (double)bbt[t]/ib - (double)bb[t]);
    double ic = (double)cg[t] / sqrt((double)cv[t] + 1e-5);
    thrc[t] = (float)((double)cm[t] - (double)cbt[t]/ic - (double)bc[t]);
  }
  if (t < 10) {
    double inv = (double)f2g[t] / sqrt((double)f2v[t] + 1e-5);
    a2[t] = (float)inv;
    c2[t] = (float)(((double)bf2[t] - (double)f2m[t]) * inv + (double)f2bt[t]);
  }
  for (int o = t; o < 1024; o += 256) {
    double inv = (double)f1g[o] / sqrt((double)f1v[o] + 1e-5);
    thrf1[o] = (float)((double)f1m[o] - (double)f1bt[o]/inv - (double)bf1[o]);
  }
  for (int w = t; w < 160; w += 256) {
    int o = w >> 4, k = w & 15;
    u64 bits = 0;
    for (int j = 0; j < 64; j++)
      if (wf2[o*1024 + k*64 + j] >= 0.f) bits |= 1ull << j;
    wf2p[w] = bits;
  }
}

// ---------------------------------------------------------------- W1: pack wf1 (ballot, coalesced)
__global__ __launch_bounds__(256) void kpackwf1(const float* __restrict__ wf1, u64* __restrict__ wf1p) {
  int gw = (blockIdx.x * 256 + threadIdx.x) >> 6;   // global word id, uniform per wave
  int lane = threadIdx.x & 63;
  if (gw >= 1024*74) return;
  int o = gw / 74, w = gw - 74*o;
  int k = w*64 + lane;
  bool bit = (k < 4704) ? (wf1[o*4704 + k] >= 0.f) : false;
  u64 m = __ballot(bit);
  if (lane == 0) wf1p[gw] = m;
}

// ---------------------------------------------------------------- A: stem conv + BN-threshold + maxpool + bitpack
__global__ __launch_bounds__(256) void kstem(const float* __restrict__ x, const char* __restrict__ ws,
                                             u16* __restrict__ h1) {
  __shared__ float xs[784];
  __shared__ float wsh[144];
  __shared__ double thr[16];
  const float* ws1 = (const float*)(ws + OFF_WS1);
  const double* thr1 = (const double*)(ws + OFF_THR1);
  int b = blockIdx.x, t = threadIdx.x;
  const float* xb = x + b*784;
  for (int i = t; i < 784; i += 256) xs[i] = xb[i];
  if (t < 144) wsh[t] = ws1[t];
  if (t < 16) thr[t] = thr1[t];
  __syncthreads();
  if (t < 196) {
    int pi = t / 14, pj = t % 14;
    u32 mm = 0;
    #pragma unroll
    for (int a = 0; a < 2; a++)
    #pragma unroll
    for (int q = 0; q < 2; q++) {
      int i = 2*pi + a, j = 2*pj + q;
      double px[9];
      #pragma unroll
      for (int dy = 0; dy < 3; dy++)
      #pragma unroll
      for (int dx = 0; dx < 3; dx++) {
        int ii = i + dy - 1, jj = j + dx - 1;
        px[dy*3+dx] = (ii >= 0 && ii < 28 && jj >= 0 && jj < 28) ? (double)xs[ii*28+jj] : 0.0;
      }
      u32 bits = 0;
      #pragma unroll
      for (int o = 0; o < 16; o++) {
        double acc = 0.0;
        #pragma unroll
        for (int k = 0; k < 9; k++) acc += px[k] * (double)wsh[o*9+k];
        if (acc >= thr[o]) bits |= 1u << o;
      }
      mm |= bits;
    }
    h1[b*196 + t] = (u16)mm;
  }
}

// ---------------------------------------------------------------- B: 3 XNOR branch convs + pool + repack to FC order
__global__ __launch_bounds__(256) void kbranch(const u16* __restrict__ h1, const char* __restrict__ ws,
                                               u64* __restrict__ h2) {
  __shared__ u16 hs[196];
  __shared__ u32 wamL[32];
  __shared__ u64 wbL[32][3];
  __shared__ u64 wcL[32][7];
  __shared__ float thA[32], thB[32], thC[32];
  __shared__ u32 r[196][3];
  __shared__ u32 pooled[49][3];
  const u32* wam = (const u32*)(ws + OFF_WAM);
  const u64* wbp = (const u64*)(ws + OFF_WBP);
  const u64* wcp = (const u64*)(ws + OFF_WCP);
  const float* thra = (const float*)(ws + OFF_THRA);
  const float* thrb = (const float*)(ws + OFF_THRB);
  const float* thrc = (const float*)(ws + OFF_THRC);
  int b = blockIdx.x, t = threadIdx.x;
  for (int i = t; i < 196; i += 256) hs[i] = h1[b*196+i];
  if (t < 32) {
    wamL[t] = wam[t]; thA[t] = thra[t]; thB[t] = thrb[t]; thC[t] = thrc[t];
    wbL[t][0]=wbp[t*3]; wbL[t][1]=wbp[t*3+1]; wbL[t][2]=wbp[t*3+2];
    #pragma unroll
    for (int k = 0; k < 7; k++) wcL[t][k] = wcp[t*8+k];
  }
  __syncthreads();
  if (t < 196) {
    int i = t/14, j = t - 14*i;
    u32 h0 = hs[t];
    u64 hqb[3] = {0,0,0}, vqb[3] = {0,0,0};
    #pragma unroll
    for (int tt = 0; tt < 9; tt++) {
      int ii = i + tt/3 - 1, jj = j + tt%3 - 1;
      if (ii>=0 && ii<14 && jj>=0 && jj<14) {
        hqb[tt>>2] |= (u64)hs[ii*14+jj] << ((tt&3)*16);
        vqb[tt>>2] |= 0xFFFFull << ((tt&3)*16);
      }
    }
    int nvb = __popcll(vqb[0]) + __popcll(vqb[1]) + __popcll(vqb[2]);
    u64 hqc[7] = {0,0,0,0,0,0,0}, vqc[7] = {0,0,0,0,0,0,0};
    #pragma unroll
    for (int tt = 0; tt < 25; tt++) {
      int ii = i + tt/5 - 2, jj = j + tt%5 - 2;
      if (ii>=0 && ii<14 && jj>=0 && jj<14) {
        hqc[tt>>2] |= (u64)hs[ii*14+jj] << ((tt&3)*16);
        vqc[tt>>2] |= 0xFFFFull << ((tt&3)*16);
      }
    }
    int nvc = 0;
    #pragma unroll
    for (int k = 0; k < 7; k++) nvc += __popcll(vqc[k]);
    u32 r0=0, r1=0, r2=0;
    for (int ch = 0; ch < 32; ch++) {
      int Sa = __popc((h0 ^ wamL[ch]) & 0xFFFFu);
      r0 |= (u32)((float)(16 - 2*Sa) >= thA[ch]) << ch;
      int Sb = 0;
      #pragma unroll
      for (int k = 0; k < 3; k++) Sb += __popcll((hqb[k] ^ wbL[ch][k]) & vqb[k]);
      r1 |= (u32)((float)(nvb - 2*Sb) >= thB[ch]) << ch;
      int Sc = 0;
      #pragma unroll
      for (int k = 0; k < 7; k++) Sc += __popcll((hqc[k] ^ wcL[ch][k]) & vqc[k]);
      r2 |= (u32)((float)(nvc - 2*Sc) >= thC[ch]) << ch;
    }
    r[t][0]=r0; r[t][1]=r1; r[t][2]=r2;
  }
  __syncthreads();
  if (t < 49) {
    int pi = t/7, pj = t - 7*pi;
    int s00 = (2*pi)*14 + 2*pj;
    #pragma unroll
    for (int q = 0; q < 3; q++)
      pooled[t][q] = r[s00][q] | r[s00+1][q] | r[s00+14][q] | r[s00+15][q];
  }
  __syncthreads();
  if (t < 74) {
    u64 word = 0;
    int f0 = t*64;
    for (int jj = 0; jj < 64; jj++) {
      int f = f0 + jj;
      if (f >= 4704) break;
      int c = f / 49, s = f - 49*c;      // flatten order f = c*49 + s (NCHW)
      word |= (u64)((pooled[s][c>>5] >> (c&31)) & 1u) << jj;
    }
    h2[b*74 + t] = word;
  }
}

// ---------------------------------------------------------------- C: FC1 XNOR-GEMM + threshold + bitpack
__global__ __launch_bounds__(256) void kfc1(const u64* __restrict__ h2, const u64* __restrict__ wf1p,
                                            const float* __restrict__ thrf1, u64* __restrict__ hb2) {
  __shared__ u64 aL[16][75];
  __shared__ u64 wL[64][75];
  __shared__ unsigned char bitsb[16][64];
  int bx = blockIdx.x, by = blockIdx.y, t = threadIdx.x;
  for (int idx = t; idx < 16*74; idx += 256) { int i = idx/74, w = idx - 74*i; aL[i][w] = h2[(by*16+i)*74 + w]; }
  for (int idx = t; idx < 64*74; idx += 256) { int o = idx/74, w = idx - 74*o; wL[o][w] = wf1p[(bx*64+o)*74 + w]; }
  __syncthreads();
  int im2 = t & 7, ou2 = t >> 3;
  int i0 = 2*im2, i1 = i0+1, o0 = 2*ou2, o1 = o0+1;
  int s00=0,s01=0,s10=0,s11=0;
  #pragma unroll 2
  for (int w = 0; w < 74; w++) {
    u64 a0 = aL[i0][w], a1 = aL[i1][w];
    u64 b0 = wL[o0][w], b1 = wL[o1][w];
    s00 += __popcll(a0^b0); s01 += __popcll(a0^b1);
    s10 += __popcll(a1^b0); s11 += __popcll(a1^b1);
  }
  float t0 = thrf1[bx*64+o0], t1 = thrf1[bx*64+o1];
  bitsb[i0][o0] = (float)(4704 - 2*s00) >= t0;
  bitsb[i0][o1] = (float)(4704 - 2*s01) >= t1;
  bitsb[i1][o0] = (float)(4704 - 2*s10) >= t0;
  bitsb[i1][o1] = (float)(4704 - 2*s11) >= t1;
  __syncthreads();
  if (t < 16) {
    u64 wd = 0;
    #pragma unroll
    for (int j = 0; j < 64; j++) wd |= (u64)bitsb[t][j] << j;
    hb2[(by*16+t)*16 + bx] = wd;
  }
}

// ---------------------------------------------------------------- D: FC2 + BN + log_softmax
__global__ __launch_bounds__(256) void kfc2(const u64* __restrict__ hb2, const char* __restrict__ ws,
                                            float* __restrict__ out, int B) {
  __shared__ u64 w2[160];
  __shared__ float a2s[10], c2s[10];
  const u64* wf2p = (const u64*)(ws + OFF_WF2P);
  const float* a2 = (const float*)(ws + OFF_A2);
  const float* c2 = (const float*)(ws + OFF_C2);
  int t = threadIdx.x;
  for (int i = t; i < 160; i += 256) w2[i] = wf2p[i];
  if (t < 10) { a2s[t] = a2[t]; c2s[t] = c2[t]; }
  __syncthreads();
  int img = blockIdx.x*256 + t;
  if (img >= B) return;
  u64 a[16];
  #pragma unroll
  for (int w = 0; w < 16; w++) a[w] = hb2[img*16 + w];
  float z[10];
  #pragma unroll
  for (int o = 0; o < 10; o++) {
    int S = 0;
    #pragma unroll
    for (int w = 0; w < 16; w++) S += __popcll(a[w] ^ w2[o*16 + w]);
    z[o] = (float)(1024 - 2*S) * a2s[o] + c2s[o];
  }
  float M = z[0];
  #pragma unroll
  for (int o = 1; o < 10; o++) M = fmaxf(M, z[o]);
  float se = 0.f;
  #pragma unroll
  for (int o = 0; o < 10; o++) se += expf(z[o] - M);
  float lse = M + logf(se);
  #pragma unroll
  for (int o = 0; o < 10; o++) out[img*10 + o] = z[o] - lse;
}

// ----------------------------------------------------------------
extern "C" void kernel_launch(void* const* d_in, const int* in_sizes, int n_in,
                              void* d_out, int out_size, void* d_ws, size_t ws_size,
                              hipStream_t stream) {
  int B = in_sizes[0] / 784;   // 4096
  char* ws = (char*)d_ws;
  InPtrs P;
  for (int i = 0; i < 37; i++) P.p[i] = (const float*)d_in[i];

  kprep<<<1, 256, 0, stream>>>(P, ws);
  kpackwf1<<<(1024*74*64)/256, 256, 0, stream>>>((const float*)d_in[25], (u64*)(ws + OFF_WF1P));
  kstem<<<B, 256, 0, stream>>>((const float*)d_in[0], ws, (u16*)(ws + OFF_H1));
  kbranch<<<B, 256, 0, stream>>>((const u16*)(ws + OFF_H1), ws, (u64*)(ws + OFF_H2));
  dim3 g(16, B/16);
  kfc1<<<g, 256, 0, stream>>>((const u64*)(ws + OFF_H2), (const u64*)(ws + OFF_WF1P),
                              (const float*)(ws + OFF_THRF1), (u64*)(ws + OFF_HB2));
  kfc2<<<(B + 255)/256, 256, 0, stream>>>((const u64*)(ws + OFF_HB2), ws, (float*)d_out, B);
}

// Round 2
// 222.180 us; speedup vs baseline: 1.9109x; 1.9109x over previous
//
#include <hip/hip_runtime.h>
#include <stdint.h>

typedef unsigned long long u64;
typedef unsigned int u32;
typedef unsigned short u16;

struct InPtrs { const float* p[37]; };

// workspace layout (bytes)
#define OFF_THR1   1024      // double[16]   stem thresholds
#define OFF_WAM    1536      // u32[32]      1x1 branch masks
#define OFF_WBP    2048      // u64[32*3]    3x3 branch masks (4 taps per u64)
#define OFF_WCP    4096      // u64[32*8]    5x5 branch masks (stride 8, 7 used)
#define OFF_THRA   6144      // float[32]
#define OFF_THRB   6400      // float[32]
#define OFF_THRC   6656      // float[32]
#define OFF_THRF1  8192      // float[1024]
#define OFF_WF2P   12288     // u64[160]
#define OFF_A2     13568     // float[10]
#define OFF_C2     13632     // float[10]
#define OFF_W1D    13824     // double[144]  stem signed weights (f64)
#define OFF_WF1P   16384     // u64[1024*74]
#define OFF_H1     655360    // u16[B*196]
#define OFF_H2     2621440   // u64[B*74]
#define OFF_HB2    5242880   // u64[B*16]

// ---------------------------------------------------------------- W0: small packs
__global__ __launch_bounds__(256) void kprep(InPtrs P, char* __restrict__ ws) {
  const float* w1 = P.p[1]; const float* b1 = P.p[2];
  const float* g1 = P.p[3]; const float* bt1 = P.p[4]; const float* m1 = P.p[5]; const float* v1 = P.p[6];
  const float* wa = P.p[7]; const float* ba = P.p[8];
  const float* ag = P.p[9]; const float* abt = P.p[10]; const float* am = P.p[11]; const float* av = P.p[12];
  const float* wb = P.p[13]; const float* bb = P.p[14];
  const float* bg = P.p[15]; const float* bbt = P.p[16]; const float* bm = P.p[17]; const float* bv = P.p[18];
  const float* wc = P.p[19]; const float* bc = P.p[20];
  const float* cg = P.p[21]; const float* cbt = P.p[22]; const float* cm = P.p[23]; const float* cv = P.p[24];
  const float* bf1 = P.p[26];
  const float* f1g = P.p[27]; const float* f1bt = P.p[28]; const float* f1m = P.p[29]; const float* f1v = P.p[30];
  const float* wf2 = P.p[31]; const float* bf2 = P.p[32];
  const float* f2g = P.p[33]; const float* f2bt = P.p[34]; const float* f2m = P.p[35]; const float* f2v = P.p[36];

  double* thr1 = (double*)(ws + OFF_THR1);
  u32* wam = (u32*)(ws + OFF_WAM);
  u64* wbp = (u64*)(ws + OFF_WBP);
  u64* wcp = (u64*)(ws + OFF_WCP);
  float* thra = (float*)(ws + OFF_THRA);
  float* thrb = (float*)(ws + OFF_THRB);
  float* thrc = (float*)(ws + OFF_THRC);
  float* thrf1 = (float*)(ws + OFF_THRF1);
  u64* wf2p = (u64*)(ws + OFF_WF2P);
  float* a2 = (float*)(ws + OFF_A2);
  float* c2 = (float*)(ws + OFF_C2);
  double* w1d = (double*)(ws + OFF_W1D);

  int t = threadIdx.x;
  for (int i = t; i < 144; i += 256) w1d[i] = (w1[i] >= 0.f) ? 1.0 : -1.0;
  if (t < 16) {
    double inv = (double)g1[t] / sqrt((double)v1[t] + 1e-5);
    thr1[t] = (double)m1[t] - (double)bt1[t] / inv - (double)b1[t];
  }
  if (t < 32) {
    u32 m = 0;
    for (int c = 0; c < 16; c++) if (wa[t*16+c] >= 0.f) m |= 1u << c;
    wam[t] = m;
    double ia = (double)ag[t] / sqrt((double)av[t] + 1e-5);
    thra[t] = (float)((double)am[t] - (double)abt[t]/ia - (double)ba[t]);
    double ib = (double)bg[t] / sqrt((double)bv[t] + 1e-5);
    thrb[t] = (float)((double)bm[t] - (double)bbt[t]/ib - (double)bb[t]);
    double ic = (double)cg[t] / sqrt((double)cv[t] + 1e-5);
    thrc[t] = (float)((double)cm[t] - (double)cbt[t]/ic - (double)bc[t]);
  }
  // wb pack: one u64 word per thread (32 ch x 3 words)
  if (t < 96) {
    int ch = t / 3, k = t - 3*ch;
    u64 q = 0;
    for (int j = 0; j < 64; j++) {
      int tt = 4*k + (j >> 4);
      if (tt < 9) {
        int c = j & 15;
        if (wb[ch*144 + c*9 + tt] >= 0.f) q |= 1ull << j;
      }
    }
    wbp[ch*3 + k] = q;
  }
  // wc pack: one u64 word per thread (32 ch x 8 words, word 7 = 0)
  {
    int ch = t >> 3, k = t & 7;
    u64 q = 0;
    if (k < 7) {
      for (int j = 0; j < 64; j++) {
        int tt = 4*k + (j >> 4);
        if (tt < 25) {
          int c = j & 15;
          if (wc[ch*400 + c*25 + tt] >= 0.f) q |= 1ull << j;
        }
      }
    }
    wcp[ch*8 + k] = q;
  }
  if (t < 10) {
    double inv = (double)f2g[t] / sqrt((double)f2v[t] + 1e-5);
    a2[t] = (float)inv;
    c2[t] = (float)(((double)bf2[t] - (double)f2m[t]) * inv + (double)f2bt[t]);
  }
  for (int o = t; o < 1024; o += 256) {
    double inv = (double)f1g[o] / sqrt((double)f1v[o] + 1e-5);
    thrf1[o] = (float)((double)f1m[o] - (double)f1bt[o]/inv - (double)bf1[o]);
  }
  for (int w = t; w < 160; w += 256) {
    int o = w >> 4, k = w & 15;
    u64 bits = 0;
    for (int j = 0; j < 64; j++)
      if (wf2[o*1024 + k*64 + j] >= 0.f) bits |= 1ull << j;
    wf2p[w] = bits;
  }
}

// ---------------------------------------------------------------- W1: pack wf1 (ballot, coalesced)
__global__ __launch_bounds__(256) void kpackwf1(const float* __restrict__ wf1, u64* __restrict__ wf1p) {
  int gw = (blockIdx.x * 256 + threadIdx.x) >> 6;   // global word id, uniform per wave
  int lane = threadIdx.x & 63;
  if (gw >= 1024*74) return;
  int o = gw / 74, w = gw - 74*o;
  int k = w*64 + lane;
  bool bit = (k < 4704) ? (wf1[o*4704 + k] >= 0.f) : false;
  u64 m = __ballot(bit);
  if (lane == 0) wf1p[gw] = m;
}

// ---------------------------------------------------------------- A: stem conv + BN-threshold + maxpool(OR) + bitpack
__global__ __launch_bounds__(256) void kstem(const float* __restrict__ x, const char* __restrict__ ws,
                                             u16* __restrict__ h1) {
  __shared__ float xs[784];
  __shared__ double wsh[144];
  __shared__ double thr[16];
  const double* w1d = (const double*)(ws + OFF_W1D);
  const double* thr1 = (const double*)(ws + OFF_THR1);
  int b = blockIdx.x, t = threadIdx.x;
  if (t < 196) reinterpret_cast<float4*>(xs)[t] =
      reinterpret_cast<const float4*>(x + b*784)[t];
  if (t >= 196 && t < 196+144) wsh[t-196] = w1d[t-196];
  if (t >= 240 && t < 256) ; // (covered above; wsh uses 196..339 -> adjust below)
  __syncthreads();
  // NOTE: wsh load above covers only indices 0..59 (t=196..255). Finish it here.
  for (int i = 60 + t, _e = 0; i < 144 && _e == 0; _e = 1) ; // no-op placeholder
  if (t < 84) wsh[60 + t] = w1d[60 + t];
  if (t >= 84 && t < 100) thr[t - 84] = thr1[t - 84];
  __syncthreads();
  if (t < 196) {
    int pi = t / 14, pj = t - 14*(t/14);
    // 4x4 patch: rows 2pi-1..2pi+2, cols 2pj-1..2pj+2, zero-padded
    double p[16];
    #pragma unroll
    for (int r = 0; r < 4; r++) {
      int ii = 2*pi - 1 + r;
      #pragma unroll
      for (int c = 0; c < 4; c++) {
        int jj = 2*pj - 1 + c;
        p[r*4+c] = (ii >= 0 && ii < 28 && jj >= 0 && jj < 28) ? (double)xs[ii*28+jj] : 0.0;
      }
    }
    u32 bits = 0;
    for (int o = 0; o < 16; o++) {
      double a00 = 0.0, a01 = 0.0, a10 = 0.0, a11 = 0.0;
      #pragma unroll
      for (int dy = 0; dy < 3; dy++) {
        #pragma unroll
        for (int dx = 0; dx < 3; dx++) {
          double w = wsh[o*9 + dy*3 + dx];
          a00 += p[dy*4 + dx]       * w;
          a01 += p[dy*4 + dx + 1]   * w;
          a10 += p[(dy+1)*4 + dx]   * w;
          a11 += p[(dy+1)*4 + dx+1] * w;
        }
      }
      double th = thr[o];
      bits |= (u32)(a00 >= th || a01 >= th || a10 >= th || a11 >= th) << o;
    }
    h1[b*196 + t] = (u16)bits;
  }
}

// ---------------------------------------------------------------- B: 3 XNOR branch convs + pool + repack to FC order
__global__ __launch_bounds__(256) void kbranch(const u16* __restrict__ h1, const char* __restrict__ ws,
                                               u64* __restrict__ h2) {
  __shared__ u16 hs[196];
  __shared__ u32 wamL[32];
  __shared__ u64 wbL[32][3];
  __shared__ u64 wcL[32][7];
  __shared__ float thA[32], thB[32], thC[32];
  __shared__ u32 r[196][3];
  __shared__ u32 pooled[49][3];
  const u32* wam = (const u32*)(ws + OFF_WAM);
  const u64* wbp = (const u64*)(ws + OFF_WBP);
  const u64* wcp = (const u64*)(ws + OFF_WCP);
  const float* thra = (const float*)(ws + OFF_THRA);
  const float* thrb = (const float*)(ws + OFF_THRB);
  const float* thrc = (const float*)(ws + OFF_THRC);
  int b = blockIdx.x, t = threadIdx.x;
  for (int i = t; i < 196; i += 256) hs[i] = h1[b*196+i];
  if (t < 32) {
    wamL[t] = wam[t]; thA[t] = thra[t]; thB[t] = thrb[t]; thC[t] = thrc[t];
    wbL[t][0]=wbp[t*3]; wbL[t][1]=wbp[t*3+1]; wbL[t][2]=wbp[t*3+2];
    #pragma unroll
    for (int k = 0; k < 7; k++) wcL[t][k] = wcp[t*8+k];
  }
  __syncthreads();
  if (t < 196) {
    int i = t/14, j = t - 14*i;
    u32 h0 = hs[t];
    u64 hqb[3] = {0,0,0}, vqb[3] = {0,0,0};
    #pragma unroll
    for (int tt = 0; tt < 9; tt++) {
      int ii = i + tt/3 - 1, jj = j + tt%3 - 1;
      if (ii>=0 && ii<14 && jj>=0 && jj<14) {
        hqb[tt>>2] |= (u64)hs[ii*14+jj] << ((tt&3)*16);
        vqb[tt>>2] |= 0xFFFFull << ((tt&3)*16);
      }
    }
    int nvb = __popcll(vqb[0]) + __popcll(vqb[1]) + __popcll(vqb[2]);
    u64 hqc[7] = {0,0,0,0,0,0,0}, vqc[7] = {0,0,0,0,0,0,0};
    #pragma unroll
    for (int tt = 0; tt < 25; tt++) {
      int ii = i + tt/5 - 2, jj = j + tt%5 - 2;
      if (ii>=0 && ii<14 && jj>=0 && jj<14) {
        hqc[tt>>2] |= (u64)hs[ii*14+jj] << ((tt&3)*16);
        vqc[tt>>2] |= 0xFFFFull << ((tt&3)*16);
      }
    }
    int nvc = 0;
    #pragma unroll
    for (int k = 0; k < 7; k++) nvc += __popcll(vqc[k]);
    u32 r0=0, r1=0, r2=0;
    for (int ch = 0; ch < 32; ch++) {
      int Sa = __popc((h0 ^ wamL[ch]) & 0xFFFFu);
      r0 |= (u32)((float)(16 - 2*Sa) >= thA[ch]) << ch;
      int Sb = 0;
      #pragma unroll
      for (int k = 0; k < 3; k++) Sb += __popcll((hqb[k] ^ wbL[ch][k]) & vqb[k]);
      r1 |= (u32)((float)(nvb - 2*Sb) >= thB[ch]) << ch;
      int Sc = 0;
      #pragma unroll
      for (int k = 0; k < 7; k++) Sc += __popcll((hqc[k] ^ wcL[ch][k]) & vqc[k]);
      r2 |= (u32)((float)(nvc - 2*Sc) >= thC[ch]) << ch;
    }
    r[t][0]=r0; r[t][1]=r1; r[t][2]=r2;
  }
  __syncthreads();
  if (t < 49) {
    int pi = t/7, pj = t - 7*pi;
    int s00 = (2*pi)*14 + 2*pj;
    #pragma unroll
    for (int q = 0; q < 3; q++)
      pooled[t][q] = r[s00][q] | r[s00+1][q] | r[s00+14][q] | r[s00+15][q];
  }
  __syncthreads();
  if (t < 74) {
    u64 word = 0;
    int f0 = t*64;
    for (int jj = 0; jj < 64; jj++) {
      int f = f0 + jj;
      if (f >= 4704) break;
      int c = f / 49, s = f - 49*c;      // flatten order f = c*49 + s (NCHW)
      word |= (u64)((pooled[s][c>>5] >> (c&31)) & 1u) << jj;
    }
    h2[b*74 + t] = word;
  }
}

// ---------------------------------------------------------------- C: FC1 XNOR-GEMM (32img x 64out blocks, b128 LDS)
__global__ __launch_bounds__(256) void kfc1(const u64* __restrict__ h2, const u64* __restrict__ wf1p,
                                            const float* __restrict__ thrf1, u64* __restrict__ hb2) {
  __shared__ __align__(16) u64 aL[32*74];
  __shared__ __align__(16) u64 wL[64*74];
  __shared__ unsigned char bitsb[32][64];
  int bx = blockIdx.x, by = blockIdx.y, t = threadIdx.x;
  const ulonglong2* ga = reinterpret_cast<const ulonglong2*>(h2 + (size_t)by*(32*74));
  ulonglong2* la = reinterpret_cast<ulonglong2*>(aL);
  for (int i = t; i < 32*37; i += 256) la[i] = ga[i];
  const ulonglong2* gw = reinterpret_cast<const ulonglong2*>(wf1p + (size_t)bx*(64*74));
  ulonglong2* lw = reinterpret_cast<ulonglong2*>(wL);
  for (int i = t; i < 64*37; i += 256) lw[i] = gw[i];
  __syncthreads();
  int ig = t & 7, og = t >> 3;            // imgs ig,ig+8,ig+16,ig+24 ; outs og,og+32
  const ulonglong2* A0 = reinterpret_cast<const ulonglong2*>(aL + ig*74);
  const ulonglong2* A1 = reinterpret_cast<const ulonglong2*>(aL + (ig+8)*74);
  const ulonglong2* A2 = reinterpret_cast<const ulonglong2*>(aL + (ig+16)*74);
  const ulonglong2* A3 = reinterpret_cast<const ulonglong2*>(aL + (ig+24)*74);
  const ulonglong2* W0 = reinterpret_cast<const ulonglong2*>(wL + og*74);
  const ulonglong2* W1 = reinterpret_cast<const ulonglong2*>(wL + (og+32)*74);
  int s00=0,s01=0,s10=0,s11=0,s20=0,s21=0,s30=0,s31=0;
  for (int w = 0; w < 37; w++) {
    ulonglong2 b0 = W0[w], b1 = W1[w];
    ulonglong2 a;
    a = A0[w]; s00 += __popcll(a.x^b0.x)+__popcll(a.y^b0.y); s01 += __popcll(a.x^b1.x)+__popcll(a.y^b1.y);
    a = A1[w]; s10 += __popcll(a.x^b0.x)+__popcll(a.y^b0.y); s11 += __popcll(a.x^b1.x)+__popcll(a.y^b1.y);
    a = A2[w]; s20 += __popcll(a.x^b0.x)+__popcll(a.y^b0.y); s21 += __popcll(a.x^b1.x)+__popcll(a.y^b1.y);
    a = A3[w]; s30 += __popcll(a.x^b0.x)+__popcll(a.y^b0.y); s31 += __popcll(a.x^b1.x)+__popcll(a.y^b1.y);
  }
  float t0 = thrf1[bx*64 + og], t1 = thrf1[bx*64 + og + 32];
  bitsb[ig   ][og] = (float)(4704 - 2*s00) >= t0;  bitsb[ig   ][og+32] = (float)(4704 - 2*s01) >= t1;
  bitsb[ig+8 ][og] = (float)(4704 - 2*s10) >= t0;  bitsb[ig+8 ][og+32] = (float)(4704 - 2*s11) >= t1;
  bitsb[ig+16][og] = (float)(4704 - 2*s20) >= t0;  bitsb[ig+16][og+32] = (float)(4704 - 2*s21) >= t1;
  bitsb[ig+24][og] = (float)(4704 - 2*s30) >= t0;  bitsb[ig+24][og+32] = (float)(4704 - 2*s31) >= t1;
  __syncthreads();
  if (t < 32) {
    u64 wd = 0;
    #pragma unroll
    for (int j = 0; j < 64; j++) wd |= (u64)bitsb[t][j] << j;
    hb2[(by*32 + t)*16 + bx] = wd;
  }
}

// ---------------------------------------------------------------- D: FC2 + BN + log_softmax
__global__ __launch_bounds__(256) void kfc2(const u64* __restrict__ hb2, const char* __restrict__ ws,
                                            float* __restrict__ out, int B) {
  __shared__ u64 w2[160];
  __shared__ float a2s[10], c2s[10];
  const u64* wf2p = (const u64*)(ws + OFF_WF2P);
  const float* a2 = (const float*)(ws + OFF_A2);
  const float* c2 = (const float*)(ws + OFF_C2);
  int t = threadIdx.x;
  for (int i = t; i < 160; i += 256) w2[i] = wf2p[i];
  if (t < 10) { a2s[t] = a2[t]; c2s[t] = c2[t]; }
  __syncthreads();
  int img = blockIdx.x*256 + t;
  if (img >= B) return;
  u64 a[16];
  #pragma unroll
  for (int w = 0; w < 16; w++) a[w] = hb2[img*16 + w];
  float z[10];
  #pragma unroll
  for (int o = 0; o < 10; o++) {
    int S = 0;
    #pragma unroll
    for (int w = 0; w < 16; w++) S += __popcll(a[w] ^ w2[o*16 + w]);
    z[o] = (float)(1024 - 2*S) * a2s[o] + c2s[o];
  }
  float M = z[0];
  #pragma unroll
  for (int o = 1; o < 10; o++) M = fmaxf(M, z[o]);
  float se = 0.f;
  #pragma unroll
  for (int o = 0; o < 10; o++) se += expf(z[o] - M);
  float lse = M + logf(se);
  #pragma unroll
  for (int o = 0; o < 10; o++) out[img*10 + o] = z[o] - lse;
}

// ----------------------------------------------------------------
extern "C" void kernel_launch(void* const* d_in, const int* in_sizes, int n_in,
                              void* d_out, int out_size, void* d_ws, size_t ws_size,
                              hipStream_t stream) {
  int B = in_sizes[0] / 784;   // 4096
  char* ws = (char*)d_ws;
  InPtrs P;
  for (int i = 0; i < 37; i++) P.p[i] = (const float*)d_in[i];

  kprep<<<1, 256, 0, stream>>>(P, ws);
  kpackwf1<<<(1024*74*64)/256, 256, 0, stream>>>((const float*)d_in[25], (u64*)(ws + OFF_WF1P));
  kstem<<<B, 256, 0, stream>>>((const float*)d_in[0], ws, (u16*)(ws + OFF_H1));
  kbranch<<<B, 256, 0, stream>>>((const u16*)(ws + OFF_H1), ws, (u64*)(ws + OFF_H2));
  dim3 g(16, B/32);
  kfc1<<<g, 256, 0, stream>>>((const u64*)(ws + OFF_H2), (const u64*)(ws + OFF_WF1P),
                              (const float*)(ws + OFF_THRF1), (u64*)(ws + OFF_HB2));
  kfc2<<<(B + 255)/256, 256, 0, stream>>>((const u64*)(ws + OFF_HB2), ws, (float*)d_out, B);
}